// Round 5
// baseline (449.065 us; speedup 1.0000x reference)
//
#include <hip/hip_runtime.h>
#include <hip/hip_bf16.h>

#define N_NODES 40000
#define N_EDGES 640000
#define IN_DIM 128
#define HIDDEN 128
#define OUT_DIM 64
#define N_GRAPHS 64
#define CAP 64   // bucket capacity per node (Poisson(16); P(max>=64) ~ 4e-15)

// ---------------------------------------------------------------------------
// Single-pass bucket scatter: cnt[d]++ and record src in d's bucket (ushort).
// ---------------------------------------------------------------------------
__global__ __launch_bounds__(256) void scatter_bucket_kernel(
    const int* __restrict__ src, const int* __restrict__ dst,
    int* __restrict__ cnt, unsigned short* __restrict__ bucket) {
  int e = blockIdx.x * 256 + threadIdx.x;
  if (e >= N_EDGES) return;
  int d = dst[e];
  int s = src[e];
  int p = atomicAdd(&cnt[d], 1);
  if (p < CAP) bucket[(size_t)d * CAP + p] = (unsigned short)s;
}

// dinv[n] = rsqrt(cnt[n] + 1)   (self-loop)
__global__ __launch_bounds__(256) void dinv_kernel(
    const int* __restrict__ cnt, float* __restrict__ dinv) {
  int n = blockIdx.x * 256 + threadIdx.x;
  if (n < N_NODES) dinv[n] = rsqrtf((float)cnt[n] + 1.0f);
}

// ---------------------------------------------------------------------------
// fp32 GEMM: C[M,128] = A[M,128] @ W[128,128]; 64-row tile, 256 threads,
// 4x8 register micro-tile per thread.
// ---------------------------------------------------------------------------
__global__ __launch_bounds__(256) void gemm_kernel(
    const float* __restrict__ A, const float* __restrict__ W,
    float* __restrict__ C) {
  __shared__ float As[8][65];
  __shared__ float Bs[8][128];
  int t = threadIdx.x;
  int tx = t & 15;
  int ty = t >> 4;
  int rowBase = blockIdx.x * 64;

  float acc[4][8];
#pragma unroll
  for (int i = 0; i < 4; ++i)
#pragma unroll
    for (int j = 0; j < 8; ++j) acc[i][j] = 0.0f;

  int arow = t >> 2;          // 0..63
  int akk = (t & 3) * 2;      // 0,2,4,6
  int bkk = t >> 5;           // 0..7
  int bcol = (t & 31) * 4;    // 0..124

  const float* Aptr = A + (size_t)(rowBase + arow) * 128 + akk;

  for (int kb = 0; kb < 128; kb += 8) {
    float2 av = *(const float2*)(Aptr + kb);
    float4 bv = *(const float4*)(W + (kb + bkk) * 128 + bcol);
    As[akk][arow] = av.x;
    As[akk + 1][arow] = av.y;
    *(float4*)&Bs[bkk][bcol] = bv;
    __syncthreads();
#pragma unroll
    for (int kk = 0; kk < 8; ++kk) {
      float a[4], b[8];
#pragma unroll
      for (int i = 0; i < 4; ++i) a[i] = As[kk][ty * 4 + i];
#pragma unroll
      for (int j = 0; j < 8; ++j) b[j] = Bs[kk][tx * 8 + j];
#pragma unroll
      for (int i = 0; i < 4; ++i)
#pragma unroll
        for (int j = 0; j < 8; ++j) acc[i][j] = fmaf(a[i], b[j], acc[i][j]);
    }
    __syncthreads();
  }

#pragma unroll
  for (int i = 0; i < 4; ++i) {
    float* cp = C + (size_t)(rowBase + ty * 4 + i) * 128 + tx * 8;
    float4 v0 = {acc[i][0], acc[i][1], acc[i][2], acc[i][3]};
    float4 v1 = {acc[i][4], acc[i][5], acc[i][6], acc[i][7]};
    *(float4*)cp = v0;
    *(float4*)(cp + 4) = v1;
  }
}

// ---------------------------------------------------------------------------
// Aggregation, paired-edge float4 gather. One wave per node.
//   lane = 32*half + c4 : half in {0,1} picks edge 2p+half of pair p,
//   c4 in [0,32) picks float4 channel block (4 channels / lane).
// One wave-load instruction fetches TWO 512B rows (1KB). Pair loop is padded
// to a multiple of 4 and hand-unrolled so 4x1KB loads stay in flight with no
// tail loop. Halves merged via shfl_xor(.,32). Edges past ecnt contribute 0
// (si/dvi zero-init -> nm=0; row 0 junk load stays cache-hot).
// pool==1: atomicAdd into per-graph sums instead of writing out.
// ---------------------------------------------------------------------------
__global__ __launch_bounds__(256) void agg_relu_kernel(
    const float* __restrict__ h, const int* __restrict__ cnt,
    const unsigned short* __restrict__ bucket,
    const float* __restrict__ dinv, const float* __restrict__ bias,
    float* __restrict__ out, const int* __restrict__ batch,
    float* __restrict__ sums, int pool) {
  int wave = threadIdx.x >> 6;
  int lane = threadIdx.x & 63;
  int n = blockIdx.x * 4 + wave;
  const float4* h4 = (const float4*)h;
  int c4 = lane & 31;
  int half = lane >> 5;

  int ecnt = min(cnt[n], CAP);
  int si = 0;
  float dvi = 0.0f;
  if (lane < ecnt) {
    si = bucket[(size_t)n * CAP + lane];
    dvi = dinv[si];
  }
  float di = dinv[n];

  float4 acc = {0.0f, 0.0f, 0.0f, 0.0f};
  int npair4 = ((ecnt + 1) >> 1 + 0);      // pairs
  npair4 = (npair4 + 3) & ~3;              // pad to multiple of 4 (max 32)
  for (int pb = 0; pb < npair4; pb += 4) {
#pragma unroll
    for (int i = 0; i < 4; ++i) {
      int e = 2 * (pb + i) + half;
      int s = __shfl(si, e);
      float nm = __shfl(dvi, e) * di;
      float4 hv = h4[(size_t)s * 32 + c4];
      acc.x = fmaf(hv.x, nm, acc.x);
      acc.y = fmaf(hv.y, nm, acc.y);
      acc.z = fmaf(hv.z, nm, acc.z);
      acc.w = fmaf(hv.w, nm, acc.w);
    }
  }

  acc.x += __shfl_xor(acc.x, 32);
  acc.y += __shfl_xor(acc.y, 32);
  acc.z += __shfl_xor(acc.z, 32);
  acc.w += __shfl_xor(acc.w, 32);

  if (half == 0) {
    float sl = di * di;
    float4 hs = h4[(size_t)n * 32 + c4];
    float4 bv = ((const float4*)bias)[c4];
    float vx = fmaxf(fmaf(sl, hs.x, acc.x) + bv.x, 0.0f);
    float vy = fmaxf(fmaf(sl, hs.y, acc.y) + bv.y, 0.0f);
    float vz = fmaxf(fmaf(sl, hs.z, acc.z) + bv.z, 0.0f);
    float vw = fmaxf(fmaf(sl, hs.w, acc.w) + bv.w, 0.0f);
    if (!pool) {
      float4 o = {vx, vy, vz, vw};
      ((float4*)out)[(size_t)n * 32 + c4] = o;
    } else {
      int g = batch[n];
      atomicAdd(&sums[g * 128 + 4 * c4 + 0], vx);
      atomicAdd(&sums[g * 128 + 4 * c4 + 1], vy);
      atomicAdd(&sums[g * 128 + 4 * c4 + 2], vz);
      atomicAdd(&sums[g * 128 + 4 * c4 + 3], vw);
    }
  }
}

// ---------------------------------------------------------------------------
// Head: per-graph count via binary search on sorted batch (folded in),
// g = sums/cnt; out = normalize(g @ Wl + bl). 1 wave per graph.
// ---------------------------------------------------------------------------
__global__ __launch_bounds__(64) void head_kernel(
    const int* __restrict__ batch, const float* __restrict__ sums,
    const float* __restrict__ Wl, const float* __restrict__ bl,
    float* __restrict__ out) {
  int g = blockIdx.x;
  int j = threadIdx.x;
  __shared__ float gv[128];
  __shared__ int bnd[2];
  if (j < 2) {
    int v = g + j;
    int lo = 0, hi = N_NODES;
    while (lo < hi) {
      int m = (lo + hi) >> 1;
      if (batch[m] < v) lo = m + 1; else hi = m;
    }
    bnd[j] = lo;
  }
  __syncthreads();
  float c = fmaxf((float)(bnd[1] - bnd[0]), 1.0f);
  float inv = 1.0f / c;
  gv[j] = sums[g * 128 + j] * inv;
  gv[j + 64] = sums[g * 128 + 64 + j] * inv;
  __syncthreads();
  float acc = bl[j];
#pragma unroll 8
  for (int k = 0; k < 128; ++k) acc = fmaf(gv[k], Wl[k * 64 + j], acc);
  float ss = acc * acc;
#pragma unroll
  for (int d = 32; d > 0; d >>= 1) ss += __shfl_xor(ss, d);
  float nrm = sqrtf(ss);
  out[g * 64 + j] = acc / fmaxf(nrm, 1e-12f);
}

// ---------------------------------------------------------------------------
extern "C" void kernel_launch(void* const* d_in, const int* in_sizes, int n_in,
                              void* d_out, int out_size, void* d_ws, size_t ws_size,
                              hipStream_t stream) {
  const float* x  = (const float*)d_in[0];
  const float* W1 = (const float*)d_in[1];
  const float* b1 = (const float*)d_in[2];
  const float* W2 = (const float*)d_in[3];
  const float* b2 = (const float*)d_in[4];
  const float* Wl = (const float*)d_in[5];
  const float* bl = (const float*)d_in[6];
  const int* edge_index = (const int*)d_in[7];   // [2, E] int32
  const int* batch = (const int*)d_in[8];
  float* out = (float*)d_out;

  const int* esrc_in = edge_index;
  const int* edst_in = edge_index + N_EDGES;

  // workspace carve-up (~46.5 MB)
  char* p = (char*)d_ws;
  float* bufA = (float*)p;  p += (size_t)N_NODES * 128 * 4;   // 20.48 MB
  float* bufB = (float*)p;  p += (size_t)N_NODES * 128 * 4;   // 20.48 MB
  int* cnt    = (int*)p;    p += (size_t)N_NODES * 4;         // 160 KB
  float* sums = (float*)p;  p += (size_t)N_GRAPHS * 128 * 4;  // 32 KB
  float* dinv = (float*)p;  p += (size_t)N_NODES * 4;         // 160 KB
  unsigned short* bucket = (unsigned short*)p;
  p += (size_t)N_NODES * CAP * 2;                              // 5.12 MB

  // zero cnt + sums in one contiguous memset (adjacent)
  hipMemsetAsync(cnt, 0, (size_t)N_NODES * 4 + (size_t)N_GRAPHS * 128 * 4,
                 stream);

  int ceilN = (N_NODES + 255) / 256;   // 157
  int ceilE = (N_EDGES + 255) / 256;   // 2500

  scatter_bucket_kernel<<<ceilE, 256, 0, stream>>>(esrc_in, edst_in, cnt, bucket);
  dinv_kernel<<<ceilN, 256, 0, stream>>>(cnt, dinv);

  // layer 1: h = x @ W1 ; agg+bias+relu -> bufB
  gemm_kernel<<<N_NODES / 64, 256, 0, stream>>>(x, W1, bufA);
  agg_relu_kernel<<<N_NODES / 4, 256, 0, stream>>>(
      bufA, cnt, bucket, dinv, b1, bufB, batch, sums, 0);

  // layer 2: h = bufB @ W2 ; agg+bias+relu fused with mean-pool accumulation
  gemm_kernel<<<N_NODES / 64, 256, 0, stream>>>(bufB, W2, bufA);
  agg_relu_kernel<<<N_NODES / 4, 256, 0, stream>>>(
      bufA, cnt, bucket, dinv, b2, nullptr, batch, sums, 1);

  // head: count via binary search, mean, linear, L2 normalize
  head_kernel<<<N_GRAPHS, 64, 0, stream>>>(batch, sums, Wl, bl, out);
}

// Round 7
// 312.970 us; speedup vs baseline: 1.4349x; 1.4349x over previous
//
#include <hip/hip_runtime.h>
#include <hip/hip_bf16.h>

#define N_NODES 40000
#define N_EDGES 640000
#define IN_DIM 128
#define HIDDEN 128
#define OUT_DIM 64
#define N_GRAPHS 64
#define CAP 64   // bucket capacity per node (Poisson(16); P(max>=64) ~ 4e-15)

// RNE round fp32->bf16, pack two into a uint (a -> low16, b -> high16)
__device__ inline unsigned int pack_bf2(float a, float b) {
  unsigned int ua = __float_as_uint(a);
  ua = ua + 0x7fffu + ((ua >> 16) & 1u);
  unsigned int ub = __float_as_uint(b);
  ub = ub + 0x7fffu + ((ub >> 16) & 1u);
  return (ua >> 16) | (ub & 0xffff0000u);
}

// ---------------------------------------------------------------------------
// Single-pass bucket scatter: cnt[d]++ and record src in d's bucket (ushort).
// ---------------------------------------------------------------------------
__global__ __launch_bounds__(256) void scatter_bucket_kernel(
    const int* __restrict__ src, const int* __restrict__ dst,
    int* __restrict__ cnt, unsigned short* __restrict__ bucket) {
  int e = blockIdx.x * 256 + threadIdx.x;
  if (e >= N_EDGES) return;
  int d = dst[e];
  int s = src[e];
  int p = atomicAdd(&cnt[d], 1);
  if (p < CAP) bucket[(size_t)d * CAP + p] = (unsigned short)s;
}

// dinv[n] = rsqrt(cnt[n] + 1)   (self-loop)
__global__ __launch_bounds__(256) void dinv_kernel(
    const int* __restrict__ cnt, float* __restrict__ dinv) {
  int n = blockIdx.x * 256 + threadIdx.x;
  if (n < N_NODES) dinv[n] = rsqrtf((float)cnt[n] + 1.0f);
}

// ---------------------------------------------------------------------------
// fp32 GEMM, bf16 output: C[M,128] = A[M,128] @ W[128,128].
// 64-row tile, 256 threads, 4x8 register micro-tile per thread.
// ---------------------------------------------------------------------------
__global__ __launch_bounds__(256) void gemm_kernel(
    const float* __restrict__ A, const float* __restrict__ W,
    unsigned int* __restrict__ C) {  // C: bf16 pairs, row stride 64 uints
  __shared__ float As[8][65];
  __shared__ float Bs[8][128];
  int t = threadIdx.x;
  int tx = t & 15;
  int ty = t >> 4;
  int rowBase = blockIdx.x * 64;

  float acc[4][8];
#pragma unroll
  for (int i = 0; i < 4; ++i)
#pragma unroll
    for (int j = 0; j < 8; ++j) acc[i][j] = 0.0f;

  int arow = t >> 2;          // 0..63
  int akk = (t & 3) * 2;      // 0,2,4,6
  int bkk = t >> 5;           // 0..7
  int bcol = (t & 31) * 4;    // 0..124

  const float* Aptr = A + (size_t)(rowBase + arow) * 128 + akk;

  for (int kb = 0; kb < 128; kb += 8) {
    float2 av = *(const float2*)(Aptr + kb);
    float4 bv = *(const float4*)(W + (kb + bkk) * 128 + bcol);
    As[akk][arow] = av.x;
    As[akk + 1][arow] = av.y;
    *(float4*)&Bs[bkk][bcol] = bv;
    __syncthreads();
#pragma unroll
    for (int kk = 0; kk < 8; ++kk) {
      float a[4], b[8];
#pragma unroll
      for (int i = 0; i < 4; ++i) a[i] = As[kk][ty * 4 + i];
#pragma unroll
      for (int j = 0; j < 8; ++j) b[j] = Bs[kk][tx * 8 + j];
#pragma unroll
      for (int i = 0; i < 4; ++i)
#pragma unroll
        for (int j = 0; j < 8; ++j) acc[i][j] = fmaf(a[i], b[j], acc[i][j]);
    }
    __syncthreads();
  }

#pragma unroll
  for (int i = 0; i < 4; ++i) {
    unsigned int* cp = C + (size_t)(rowBase + ty * 4 + i) * 64 + tx * 4;
    uint4 v;
    v.x = pack_bf2(acc[i][0], acc[i][1]);
    v.y = pack_bf2(acc[i][2], acc[i][3]);
    v.z = pack_bf2(acc[i][4], acc[i][5]);
    v.w = pack_bf2(acc[i][6], acc[i][7]);
    *(uint4*)cp = v;
  }
}

// ---------------------------------------------------------------------------
// Aggregation over bf16 h. One wave per node; lane owns channels 2l,2l+1
// (one uint = 2 bf16 per lane -> 256B per row per wave-instruction).
// Broadcast index e is WAVE-UNIFORM -> v_readlane (SGPR base, coalesced
// single-segment gather). fp32 accumulate. Loop padded to multiple of 8,
// hand-unrolled: 8 independent loads in flight. Junk iters (e>=ecnt) load
// row 0 (uniform, cache-hot) with nm=0.
// pool==1: atomicAdd into per-graph sums instead of writing out.
// ---------------------------------------------------------------------------
__global__ __launch_bounds__(256) void agg_relu_kernel(
    const unsigned int* __restrict__ h, const int* __restrict__ cnt,
    const unsigned short* __restrict__ bucket,
    const float* __restrict__ dinv, const float* __restrict__ bias,
    float* __restrict__ out, const int* __restrict__ batch,
    float* __restrict__ sums, int pool) {
  int wave = threadIdx.x >> 6;
  int lane = threadIdx.x & 63;
  int n = blockIdx.x * 4 + wave;

  int ecnt = min(cnt[n], CAP);
  int si = 0;
  float dvi = 0.0f;
  if (lane < ecnt) {
    si = bucket[(size_t)n * CAP + lane];
    dvi = dinv[si];
  }
  float di = dinv[n];

  float accx = 0.0f, accy = 0.0f;
  int iters = (ecnt + 7) & ~7;   // pad to multiple of 8 (max 64)
  for (int eb = 0; eb < iters; eb += 8) {
#pragma unroll
    for (int i = 0; i < 8; ++i) {
      int e = eb + i;                     // wave-uniform
      int s = __shfl(si, e);              // -> readlane, SGPR
      float nm = __shfl(dvi, e) * di;
      unsigned int hv = h[(size_t)s * 64 + lane];
      float hx = __uint_as_float(hv << 16);
      float hy = __uint_as_float(hv & 0xffff0000u);
      accx = fmaf(hx, nm, accx);
      accy = fmaf(hy, nm, accy);
    }
  }

  float sl = di * di;
  unsigned int hsv = h[(size_t)n * 64 + lane];
  float hsx = __uint_as_float(hsv << 16);
  float hsy = __uint_as_float(hsv & 0xffff0000u);
  float2 bv = ((const float2*)bias)[lane];
  float vx = fmaxf(fmaf(sl, hsx, accx) + bv.x, 0.0f);
  float vy = fmaxf(fmaf(sl, hsy, accy) + bv.y, 0.0f);

  if (!pool) {
    float2 o = {vx, vy};
    ((float2*)out)[(size_t)n * 64 + lane] = o;
  } else {
    int g = batch[n];
    atomicAdd(&sums[g * 128 + 2 * lane], vx);
    atomicAdd(&sums[g * 128 + 2 * lane + 1], vy);
  }
}

// ---------------------------------------------------------------------------
// Head: per-graph count via binary search on sorted batch (folded in),
// g = sums/cnt; out = normalize(g @ Wl + bl). 1 wave per graph.
// ---------------------------------------------------------------------------
__global__ __launch_bounds__(64) void head_kernel(
    const int* __restrict__ batch, const float* __restrict__ sums,
    const float* __restrict__ Wl, const float* __restrict__ bl,
    float* __restrict__ out) {
  int g = blockIdx.x;
  int j = threadIdx.x;
  __shared__ float gv[128];
  __shared__ int bnd[2];
  if (j < 2) {
    int v = g + j;
    int lo = 0, hi = N_NODES;
    while (lo < hi) {
      int m = (lo + hi) >> 1;
      if (batch[m] < v) lo = m + 1; else hi = m;
    }
    bnd[j] = lo;
  }
  __syncthreads();
  float c = fmaxf((float)(bnd[1] - bnd[0]), 1.0f);
  float inv = 1.0f / c;
  gv[j] = sums[g * 128 + j] * inv;
  gv[j + 64] = sums[g * 128 + 64 + j] * inv;
  __syncthreads();
  float acc = bl[j];
#pragma unroll 8
  for (int k = 0; k < 128; ++k) acc = fmaf(gv[k], Wl[k * 64 + j], acc);
  float ss = acc * acc;
#pragma unroll
  for (int d = 32; d > 0; d >>= 1) ss += __shfl_xor(ss, d);
  float nrm = sqrtf(ss);
  out[g * 64 + j] = acc / fmaxf(nrm, 1e-12f);
}

// ---------------------------------------------------------------------------
extern "C" void kernel_launch(void* const* d_in, const int* in_sizes, int n_in,
                              void* d_out, int out_size, void* d_ws, size_t ws_size,
                              hipStream_t stream) {
  const float* x  = (const float*)d_in[0];
  const float* W1 = (const float*)d_in[1];
  const float* b1 = (const float*)d_in[2];
  const float* W2 = (const float*)d_in[3];
  const float* b2 = (const float*)d_in[4];
  const float* Wl = (const float*)d_in[5];
  const float* bl = (const float*)d_in[6];
  const int* edge_index = (const int*)d_in[7];   // [2, E] int32
  const int* batch = (const int*)d_in[8];
  float* out = (float*)d_out;

  const int* esrc_in = edge_index;
  const int* edst_in = edge_index + N_EDGES;

  // workspace carve-up (~36.2 MB)
  char* p = (char*)d_ws;
  unsigned int* bufA = (unsigned int*)p;                      // bf16 h (pairs)
  p += (size_t)N_NODES * 64 * 4;                              // 10.24 MB
  float* bufB = (float*)p;  p += (size_t)N_NODES * 128 * 4;   // 20.48 MB
  int* cnt    = (int*)p;    p += (size_t)N_NODES * 4;         // 160 KB
  float* sums = (float*)p;  p += (size_t)N_GRAPHS * 128 * 4;  // 32 KB
  float* dinv = (float*)p;  p += (size_t)N_NODES * 4;         // 160 KB
  unsigned short* bucket = (unsigned short*)p;
  p += (size_t)N_NODES * CAP * 2;                              // 5.12 MB

  // zero cnt + sums in one contiguous memset (adjacent)
  hipMemsetAsync(cnt, 0, (size_t)N_NODES * 4 + (size_t)N_GRAPHS * 128 * 4,
                 stream);

  int ceilN = (N_NODES + 255) / 256;   // 157
  int ceilE = (N_EDGES + 255) / 256;   // 2500

  scatter_bucket_kernel<<<ceilE, 256, 0, stream>>>(esrc_in, edst_in, cnt, bucket);
  dinv_kernel<<<ceilN, 256, 0, stream>>>(cnt, dinv);

  // layer 1: h = bf16(x @ W1) ; agg+bias+relu -> bufB (fp32)
  gemm_kernel<<<N_NODES / 64, 256, 0, stream>>>(x, W1, bufA);
  agg_relu_kernel<<<N_NODES / 4, 256, 0, stream>>>(
      bufA, cnt, bucket, dinv, b1, bufB, batch, sums, 0);

  // layer 2: h = bf16(bufB @ W2) ; agg+bias+relu fused with mean-pool accum
  gemm_kernel<<<N_NODES / 64, 256, 0, stream>>>(bufB, W2, bufA);
  agg_relu_kernel<<<N_NODES / 4, 256, 0, stream>>>(
      bufA, cnt, bucket, dinv, b2, nullptr, batch, sums, 1);

  // head: count via binary search, mean, linear, L2 normalize
  head_kernel<<<N_GRAPHS, 64, 0, stream>>>(batch, sums, Wl, bl, out);
}

// Round 8
// 310.769 us; speedup vs baseline: 1.4450x; 1.0071x over previous
//
#include <hip/hip_runtime.h>
#include <hip/hip_bf16.h>

#define N_NODES 40000
#define N_EDGES 640000
#define IN_DIM 128
#define HIDDEN 128
#define OUT_DIM 64
#define N_GRAPHS 64
#define CAP 64   // bucket capacity per node (Poisson(16); P(max>=64) ~ 4e-15)

// RNE round fp32->bf16, pack two into a uint (a -> low16, b -> high16)
__device__ inline unsigned int pack_bf2(float a, float b) {
  unsigned int ua = __float_as_uint(a);
  ua = ua + 0x7fffu + ((ua >> 16) & 1u);
  unsigned int ub = __float_as_uint(b);
  ub = ub + 0x7fffu + ((ub >> 16) & 1u);
  return (ua >> 16) | (ub & 0xffff0000u);
}

// ---------------------------------------------------------------------------
// Single-pass bucket scatter: cnt[d]++ and record src in d's bucket (ushort).
// ---------------------------------------------------------------------------
__global__ __launch_bounds__(256) void scatter_bucket_kernel(
    const int* __restrict__ src, const int* __restrict__ dst,
    int* __restrict__ cnt, unsigned short* __restrict__ bucket) {
  int e = blockIdx.x * 256 + threadIdx.x;
  if (e >= N_EDGES) return;
  int d = dst[e];
  int s = src[e];
  int p = atomicAdd(&cnt[d], 1);
  if (p < CAP) bucket[(size_t)d * CAP + p] = (unsigned short)s;
}

// dinv[n] = rsqrt(cnt[n] + 1)   (self-loop)
__global__ __launch_bounds__(256) void dinv_kernel(
    const int* __restrict__ cnt, float* __restrict__ dinv) {
  int n = blockIdx.x * 256 + threadIdx.x;
  if (n < N_NODES) dinv[n] = rsqrtf((float)cnt[n] + 1.0f);
}

// ---------------------------------------------------------------------------
// Finalize: one wave per node. Re-pack bucket entry -> uint:
//   (bf16(dinv[src]) << 16) | src
// Does the random dinv gather ONCE so both agg passes read it coalesced and
// need only ONE shfl per edge. Empty slots -> 0 (src 0, norm +0.0).
// ---------------------------------------------------------------------------
__global__ __launch_bounds__(256) void finalize_kernel(
    const int* __restrict__ cnt, const unsigned short* __restrict__ bucket,
    const float* __restrict__ dinv, unsigned int* __restrict__ bucket2) {
  int wave = threadIdx.x >> 6;
  int lane = threadIdx.x & 63;
  int n = blockIdx.x * 4 + wave;
  int ecnt = min(cnt[n], CAP);
  unsigned int v = 0;
  if (lane < ecnt) {
    int s = bucket[(size_t)n * CAP + lane];
    unsigned int d = __float_as_uint(dinv[s]);
    d = d + 0x7fffu + ((d >> 16) & 1u);          // RNE to bf16
    v = (d & 0xffff0000u) | (unsigned int)s;
  }
  bucket2[(size_t)n * CAP + lane] = v;
}

// ---------------------------------------------------------------------------
// fp32 GEMM, bf16 output: C[M,128] = A[M,128] @ W[128,128].
// 64-row tile, 256 threads, 4x8 register micro-tile per thread.
// ---------------------------------------------------------------------------
__global__ __launch_bounds__(256) void gemm_kernel(
    const float* __restrict__ A, const float* __restrict__ W,
    unsigned int* __restrict__ C) {  // C: bf16 pairs, row stride 64 uints
  __shared__ float As[8][65];
  __shared__ float Bs[8][128];
  int t = threadIdx.x;
  int tx = t & 15;
  int ty = t >> 4;
  int rowBase = blockIdx.x * 64;

  float acc[4][8];
#pragma unroll
  for (int i = 0; i < 4; ++i)
#pragma unroll
    for (int j = 0; j < 8; ++j) acc[i][j] = 0.0f;

  int arow = t >> 2;          // 0..63
  int akk = (t & 3) * 2;      // 0,2,4,6
  int bkk = t >> 5;           // 0..7
  int bcol = (t & 31) * 4;    // 0..124

  const float* Aptr = A + (size_t)(rowBase + arow) * 128 + akk;

  for (int kb = 0; kb < 128; kb += 8) {
    float2 av = *(const float2*)(Aptr + kb);
    float4 bv = *(const float4*)(W + (kb + bkk) * 128 + bcol);
    As[akk][arow] = av.x;
    As[akk + 1][arow] = av.y;
    *(float4*)&Bs[bkk][bcol] = bv;
    __syncthreads();
#pragma unroll
    for (int kk = 0; kk < 8; ++kk) {
      float a[4], b[8];
#pragma unroll
      for (int i = 0; i < 4; ++i) a[i] = As[kk][ty * 4 + i];
#pragma unroll
      for (int j = 0; j < 8; ++j) b[j] = Bs[kk][tx * 8 + j];
#pragma unroll
      for (int i = 0; i < 4; ++i)
#pragma unroll
        for (int j = 0; j < 8; ++j) acc[i][j] = fmaf(a[i], b[j], acc[i][j]);
    }
    __syncthreads();
  }

#pragma unroll
  for (int i = 0; i < 4; ++i) {
    unsigned int* cp = C + (size_t)(rowBase + ty * 4 + i) * 64 + tx * 4;
    uint4 v;
    v.x = pack_bf2(acc[i][0], acc[i][1]);
    v.y = pack_bf2(acc[i][2], acc[i][3]);
    v.z = pack_bf2(acc[i][4], acc[i][5]);
    v.w = pack_bf2(acc[i][6], acc[i][7]);
    *(uint4*)cp = v;
  }
}

// ---------------------------------------------------------------------------
// Aggregation over bf16 h. One wave per node; lane owns channels 2l,2l+1.
// Setup: ONE coalesced uint load (src | bf16 dinv packed). Inner loop: one
// wave-uniform shfl (readlane) decodes both src and norm; 16 independent
// 256B gathers issued back-to-back per drain point (unroll 16). Junk iters
// (slot empty) load row 0 with nm=0. fp32 accumulate.
// pool==1: atomicAdd into per-graph sums instead of writing out.
// ---------------------------------------------------------------------------
__global__ __launch_bounds__(256) void agg_relu_kernel(
    const unsigned int* __restrict__ h, const int* __restrict__ cnt,
    const unsigned int* __restrict__ bucket2,
    const float* __restrict__ dinv, const float* __restrict__ bias,
    float* __restrict__ out, const int* __restrict__ batch,
    float* __restrict__ sums, int pool) {
  int wave = threadIdx.x >> 6;
  int lane = threadIdx.x & 63;
  int n = blockIdx.x * 4 + wave;

  unsigned int ev = bucket2[(size_t)n * CAP + lane];  // coalesced, 256B/wave
  int ecnt = min(cnt[n], CAP);
  float di = dinv[n];

  float accx = 0.0f, accy = 0.0f;
  int iters = (ecnt + 15) & ~15;   // pad to multiple of 16 (16..64)
  for (int eb = 0; eb < iters; eb += 16) {
#pragma unroll
    for (int i = 0; i < 16; ++i) {
      int e = eb + i;                         // wave-uniform
      unsigned int edge = __shfl(ev, e);      // -> readlane, SGPR
      int s = edge & 0xffffu;
      float nm = __uint_as_float(edge & 0xffff0000u) * di;
      unsigned int hv = h[(size_t)s * 64 + lane];
      float hx = __uint_as_float(hv << 16);
      float hy = __uint_as_float(hv & 0xffff0000u);
      accx = fmaf(hx, nm, accx);
      accy = fmaf(hy, nm, accy);
    }
  }

  float sl = di * di;
  unsigned int hsv = h[(size_t)n * 64 + lane];
  float hsx = __uint_as_float(hsv << 16);
  float hsy = __uint_as_float(hsv & 0xffff0000u);
  float2 bv = ((const float2*)bias)[lane];
  float vx = fmaxf(fmaf(sl, hsx, accx) + bv.x, 0.0f);
  float vy = fmaxf(fmaf(sl, hsy, accy) + bv.y, 0.0f);

  if (!pool) {
    float2 o = {vx, vy};
    ((float2*)out)[(size_t)n * 64 + lane] = o;
  } else {
    int g = batch[n];
    atomicAdd(&sums[g * 128 + 2 * lane], vx);
    atomicAdd(&sums[g * 128 + 2 * lane + 1], vy);
  }
}

// ---------------------------------------------------------------------------
// Head: per-graph count via binary search on sorted batch (folded in),
// g = sums/cnt; out = normalize(g @ Wl + bl). 1 wave per graph.
// ---------------------------------------------------------------------------
__global__ __launch_bounds__(64) void head_kernel(
    const int* __restrict__ batch, const float* __restrict__ sums,
    const float* __restrict__ Wl, const float* __restrict__ bl,
    float* __restrict__ out) {
  int g = blockIdx.x;
  int j = threadIdx.x;
  __shared__ float gv[128];
  __shared__ int bnd[2];
  if (j < 2) {
    int v = g + j;
    int lo = 0, hi = N_NODES;
    while (lo < hi) {
      int m = (lo + hi) >> 1;
      if (batch[m] < v) lo = m + 1; else hi = m;
    }
    bnd[j] = lo;
  }
  __syncthreads();
  float c = fmaxf((float)(bnd[1] - bnd[0]), 1.0f);
  float inv = 1.0f / c;
  gv[j] = sums[g * 128 + j] * inv;
  gv[j + 64] = sums[g * 128 + 64 + j] * inv;
  __syncthreads();
  float acc = bl[j];
#pragma unroll 8
  for (int k = 0; k < 128; ++k) acc = fmaf(gv[k], Wl[k * 64 + j], acc);
  float ss = acc * acc;
#pragma unroll
  for (int d = 32; d > 0; d >>= 1) ss += __shfl_xor(ss, d);
  float nrm = sqrtf(ss);
  out[g * 64 + j] = acc / fmaxf(nrm, 1e-12f);
}

// ---------------------------------------------------------------------------
extern "C" void kernel_launch(void* const* d_in, const int* in_sizes, int n_in,
                              void* d_out, int out_size, void* d_ws, size_t ws_size,
                              hipStream_t stream) {
  const float* x  = (const float*)d_in[0];
  const float* W1 = (const float*)d_in[1];
  const float* b1 = (const float*)d_in[2];
  const float* W2 = (const float*)d_in[3];
  const float* b2 = (const float*)d_in[4];
  const float* Wl = (const float*)d_in[5];
  const float* bl = (const float*)d_in[6];
  const int* edge_index = (const int*)d_in[7];   // [2, E] int32
  const int* batch = (const int*)d_in[8];
  float* out = (float*)d_out;

  const int* esrc_in = edge_index;
  const int* edst_in = edge_index + N_EDGES;

  // workspace carve-up (~46.5 MB)
  char* p = (char*)d_ws;
  unsigned int* bufA = (unsigned int*)p;                      // bf16 h (pairs)
  p += (size_t)N_NODES * 64 * 4;                              // 10.24 MB
  float* bufB = (float*)p;  p += (size_t)N_NODES * 128 * 4;   // 20.48 MB
  int* cnt    = (int*)p;    p += (size_t)N_NODES * 4;         // 160 KB
  float* sums = (float*)p;  p += (size_t)N_GRAPHS * 128 * 4;  // 32 KB
  float* dinv = (float*)p;  p += (size_t)N_NODES * 4;         // 160 KB
  unsigned short* bucket = (unsigned short*)p;
  p += (size_t)N_NODES * CAP * 2;                              // 5.12 MB
  unsigned int* bucket2 = (unsigned int*)p;
  p += (size_t)N_NODES * CAP * 4;                              // 10.24 MB

  // zero cnt + sums in one contiguous memset (adjacent)
  hipMemsetAsync(cnt, 0, (size_t)N_NODES * 4 + (size_t)N_GRAPHS * 128 * 4,
                 stream);

  int ceilN = (N_NODES + 255) / 256;   // 157
  int ceilE = (N_EDGES + 255) / 256;   // 2500

  scatter_bucket_kernel<<<ceilE, 256, 0, stream>>>(esrc_in, edst_in, cnt, bucket);
  dinv_kernel<<<ceilN, 256, 0, stream>>>(cnt, dinv);
  finalize_kernel<<<N_NODES / 4, 256, 0, stream>>>(cnt, bucket, dinv, bucket2);

  // layer 1: h = bf16(x @ W1) ; agg+bias+relu -> bufB (fp32)
  gemm_kernel<<<N_NODES / 64, 256, 0, stream>>>(x, W1, bufA);
  agg_relu_kernel<<<N_NODES / 4, 256, 0, stream>>>(
      bufA, cnt, bucket2, dinv, b1, bufB, batch, sums, 0);

  // layer 2: h = bf16(bufB @ W2) ; agg+bias+relu fused with mean-pool accum
  gemm_kernel<<<N_NODES / 64, 256, 0, stream>>>(bufB, W2, bufA);
  agg_relu_kernel<<<N_NODES / 4, 256, 0, stream>>>(
      bufA, cnt, bucket2, dinv, b2, nullptr, batch, sums, 1);

  // head: count via binary search, mean, linear, L2 normalize
  head_kernel<<<N_GRAPHS, 64, 0, stream>>>(batch, sums, Wl, bl, out);
}